// Round 6
// baseline (461.808 us; speedup 1.0000x reference)
//
#include <hip/hip_runtime.h>

#define N_NODES 50000
#define N_EDGES 600000
#define DIM 128
#define N_LAYERS 4
#define N_GRAPHS 64
#define NEG_SLOPE 0.01f
#define NB_SCAN ((N_NODES + 255) / 256)  // 196 blocks
#define RS 264  // LDS row stride in bf16 elems: 256 data + 8 pad (16B)

typedef __attribute__((ext_vector_type(8))) short short8;
typedef __attribute__((ext_vector_type(16))) float floatx16;

__device__ __forceinline__ unsigned short f2bf(float f) {
    union { float f; unsigned u; } c; c.f = f;
    unsigned u = c.u;
    unsigned r = (u + 0x7FFFu + ((u >> 16) & 1u)) >> 16;
    return (unsigned short)r;
}
__device__ __forceinline__ float bfraw2f(unsigned short b) {
    union { unsigned u; float f; } c; c.u = ((unsigned)b) << 16;
    return c.f;
}
__device__ __forceinline__ float bflo(unsigned u) {
    union { unsigned u; float f; } c; c.u = u << 16; return c.f;
}
__device__ __forceinline__ float bfhi(unsigned u) {
    union { unsigned u; float f; } c; c.u = u & 0xFFFF0000u; return c.f;
}

// ---------------- utility kernels ----------------

__global__ void zero_ints(int* p, int n) {
    int i = blockIdx.x * blockDim.x + threadIdx.x;
    if (i < n) p[i] = 0;
}

// convert fp32 x -> bf16 (8 elems per thread)
__global__ void convert_x(const float4* __restrict__ x, uint4* __restrict__ xb) {
    int i = blockIdx.x * blockDim.x + threadIdx.x;  // chunk of 8 floats
    if (i >= N_NODES * DIM / 8) return;
    float4 a = x[i * 2], b = x[i * 2 + 1];
    uint4 o;
    o.x = ((unsigned)f2bf(a.y) << 16) | f2bf(a.x);
    o.y = ((unsigned)f2bf(a.w) << 16) | f2bf(a.z);
    o.z = ((unsigned)f2bf(b.y) << 16) | f2bf(b.x);
    o.w = ((unsigned)f2bf(b.w) << 16) | f2bf(b.z);
    xb[i] = o;
}

// pack weights into MFMA B-fragment order (bf16), for v_mfma_f32_32x32x16_bf16.
// B[k][n] = W[n][k]. Fragment (layer, m, s, t): lane l holds B[s*16+(l>>5)*8+j][t*32+(l&31)], j=0..7.
__global__ void pack_w(const float* __restrict__ Wl, const float* __restrict__ Wr,
                       ushort* __restrict__ wpk) {
    int s = blockIdx.x >> 2, t = blockIdx.x & 3;
    int m = blockIdx.y, layer = blockIdx.z;
    int l = threadIdx.x;  // 64 lanes
    const float* W = ((m == 0) ? Wl : Wr) + (size_t)layer * DIM * DIM;
    int n = t * 32 + (l & 31);
    int kb = s * 16 + (l >> 5) * 8;
    size_t off = ((((size_t)(layer * 2 + m) * 8 + s) * 4 + t) * 64 + l) * 8;
    for (int j = 0; j < 8; j++)
        wpk[off + j] = f2bf(W[n * DIM + kb + j]);
}

__global__ void count_deg(const int* __restrict__ dst, int* deg) {
    int e = blockIdx.x * blockDim.x + threadIdx.x;
    if (e < N_EDGES) atomicAdd(&deg[dst[e]], 1);
}

// ---------------- 3-pass exclusive scan of deg -> rp ----------------
__global__ void scan_pass1(const int* __restrict__ deg, int* __restrict__ bsum) {
    int i = blockIdx.x * 256 + threadIdx.x;
    int v = (i < N_NODES) ? deg[i] : 0;
    for (int off = 32; off > 0; off >>= 1) v += __shfl_down(v, off, 64);
    __shared__ int ws[4];
    int lane = threadIdx.x & 63, w = threadIdx.x >> 6;
    if (lane == 0) ws[w] = v;
    __syncthreads();
    if (threadIdx.x == 0) bsum[blockIdx.x] = ws[0] + ws[1] + ws[2] + ws[3];
}

__global__ void scan_pass2(int* __restrict__ bsum) {
    __shared__ int sm[256];
    int t = threadIdx.x;
    int v = (t < NB_SCAN) ? bsum[t] : 0;
    sm[t] = v;
    __syncthreads();
    for (int off = 1; off < 256; off <<= 1) {
        int u = (t >= off) ? sm[t - off] : 0;
        __syncthreads();
        sm[t] += u;
        __syncthreads();
    }
    if (t < NB_SCAN) bsum[t] = sm[t] - v;
}

__global__ void scan_pass3(const int* __restrict__ deg, const int* __restrict__ bsum,
                           int* __restrict__ rp) {
    int i = blockIdx.x * 256 + threadIdx.x;
    int v = (i < N_NODES) ? deg[i] : 0;
    int lane = threadIdx.x & 63, w = threadIdx.x >> 6;
    int s = v;
    for (int off = 1; off < 64; off <<= 1) {
        int t = __shfl_up(s, off, 64);
        if (lane >= off) s += t;
    }
    __shared__ int ws[4];
    if (lane == 63) ws[w] = s;
    __syncthreads();
    int wo = 0;
    for (int k = 0; k < 4; k++) wo += (k < w) ? ws[k] : 0;
    int incl = s + wo + bsum[blockIdx.x];
    if (i < N_NODES) rp[i + 1] = incl;
    if (i == 0) rp[0] = 0;
}

__global__ void fill_csr(const int* __restrict__ src, const int* __restrict__ dst,
                         const int* __restrict__ rp, int* __restrict__ fill,
                         int* __restrict__ csr) {
    int e = blockIdx.x * blockDim.x + threadIdx.x;
    if (e >= N_EDGES) return;
    int d = dst[e];
    int pos = atomicAdd(&fill[d], 1);
    csr[rp[d] + pos] = src[e];
}

__global__ void graph_start(const int* __restrict__ batch, int* __restrict__ gstart) {
    int i = blockIdx.x * blockDim.x + threadIdx.x;
    if (i >= N_NODES) return;
    int b = batch[i];
    if (i == 0) {
        for (int g = 0; g <= b; g++) gstart[g] = 0;
    } else {
        int p = batch[i - 1];
        for (int g = p + 1; g <= b; g++) gstart[g] = i;
    }
    if (i == N_NODES - 1) {
        for (int g = b + 1; g <= N_GRAPHS; g++) gstart[g] = N_NODES;
    }
}

// ---------------- fused SAGE layer: gather-aggregate + dual GEMM (MFMA) ----------------
// Block: 128 nodes, 4 waves, NO __syncthreads (each wave owns its 32 rows of LDS).
// Gather: dwordx4 per lane; 64 lanes = 4 full 256B rows per load instruction.
// lane = eg*16 + ll : eg in [0,4) selects edge, ll in [0,16) selects 16B chunk of row.
__global__ __launch_bounds__(256) void sage_layer(const uint* __restrict__ x32,
                                                  ushort* __restrict__ xout,
                                                  const int* __restrict__ rp,
                                                  const int* __restrict__ csr,
                                                  const ushort* __restrict__ wpk,
                                                  const float* __restrict__ bias,
                                                  int residual) {
    __shared__ ushort sA[128 * RS];  // row r: [agg(128) | x(128) | pad(8)]
    int t = threadIdx.x;
    int wv = t >> 6, lane = t & 63;
    int node0 = blockIdx.x * 128;
    int m0 = wv * 32;
    int ll = lane & 15, eg = lane >> 4;

    const uint4* x16B = (const uint4*)x32;  // row = 16 uint4 chunks

    // ---- per-wave: aggregate + stage 32 rows (2 nodes interleaved for MLP) ----
    for (int i = 0; i < 32; i += 2) {
        int rA = m0 + i, rB = rA + 1;
        int nA = node0 + rA, nB = node0 + rB;
        int sAe = 0, eAe = 0, sBe = 0, eBe = 0;
        if (nA < N_NODES) { sAe = rp[nA]; eAe = rp[nA + 1]; }
        if (nB < N_NODES) { sBe = rp[nB]; eBe = rp[nB + 1]; }

        // stage x rows (coalesced 256B per row)
        unsigned xvA = (nA < N_NODES) ? x32[(size_t)nA * 64 + lane] : 0u;
        unsigned xvB = (nB < N_NODES) ? x32[(size_t)nB * 64 + lane] : 0u;
        ((uint*)(sA + (size_t)rA * RS))[64 + lane] = xvA;
        ((uint*)(sA + (size_t)rB * RS))[64 + lane] = xvB;

        float accA[8] = {0.f}, accB[8] = {0.f};
        int baseA = sAe, baseB = sBe;
        while (baseA < eAe || baseB < eBe) {
            int cntA = (baseA < eAe) ? min(64, eAe - baseA) : 0;
            int cntB = (baseB < eBe) ? min(64, eBe - baseB) : 0;
            unsigned idxA = (baseA + lane < eAe) ? (unsigned)csr[baseA + lane] : 0u;
            unsigned idxB = (baseB + lane < eBe) ? (unsigned)csr[baseB + lane] : 0u;
            int mx = max(cntA, cntB);
            for (int j = 0; j < mx; j += 4) {
                int sel = j + eg;
                unsigned iA = __shfl(idxA, sel & 63, 64);
                unsigned iB = __shfl(idxB, sel & 63, 64);
                uint4 vA = make_uint4(0u, 0u, 0u, 0u);
                uint4 vB = make_uint4(0u, 0u, 0u, 0u);
                if (sel < cntA) vA = x16B[(size_t)iA * 16 + ll];
                if (sel < cntB) vB = x16B[(size_t)iB * 16 + ll];
                accA[0] += bflo(vA.x); accA[1] += bfhi(vA.x);
                accA[2] += bflo(vA.y); accA[3] += bfhi(vA.y);
                accA[4] += bflo(vA.z); accA[5] += bfhi(vA.z);
                accA[6] += bflo(vA.w); accA[7] += bfhi(vA.w);
                accB[0] += bflo(vB.x); accB[1] += bfhi(vB.x);
                accB[2] += bflo(vB.y); accB[3] += bfhi(vB.y);
                accB[4] += bflo(vB.z); accB[5] += bfhi(vB.z);
                accB[6] += bflo(vB.w); accB[7] += bfhi(vB.w);
            }
            baseA += 64; baseB += 64;
        }
        // reduce across the 4 edge-groups (lane^16, lane^32)
#pragma unroll
        for (int k = 0; k < 8; k++) {
            accA[k] += __shfl_xor(accA[k], 16, 64);
            accA[k] += __shfl_xor(accA[k], 32, 64);
            accB[k] += __shfl_xor(accB[k], 16, 64);
            accB[k] += __shfl_xor(accB[k], 32, 64);
        }
        float invA = 1.0f / (float)max(eAe - sAe, 1);
        float invB = 1.0f / (float)max(eBe - sBe, 1);
        if (eg == 0) {
            uint4 oA, oB;
            oA.x = ((unsigned)f2bf(accA[1] * invA) << 16) | f2bf(accA[0] * invA);
            oA.y = ((unsigned)f2bf(accA[3] * invA) << 16) | f2bf(accA[2] * invA);
            oA.z = ((unsigned)f2bf(accA[5] * invA) << 16) | f2bf(accA[4] * invA);
            oA.w = ((unsigned)f2bf(accA[7] * invA) << 16) | f2bf(accA[6] * invA);
            oB.x = ((unsigned)f2bf(accB[1] * invB) << 16) | f2bf(accB[0] * invB);
            oB.y = ((unsigned)f2bf(accB[3] * invB) << 16) | f2bf(accB[2] * invB);
            oB.z = ((unsigned)f2bf(accB[5] * invB) << 16) | f2bf(accB[4] * invB);
            oB.w = ((unsigned)f2bf(accB[7] * invB) << 16) | f2bf(accB[6] * invB);
            ((uint4*)(sA + (size_t)rA * RS))[ll] = oA;
            ((uint4*)(sA + (size_t)rB * RS))[ll] = oB;
        }
    }
    // no __syncthreads: each wave reads only its own 32 LDS rows below

    // ---- MFMA: wave computes rows m0..m0+31 x all 128 outputs ----
    const ushort* arow = &sA[(size_t)(m0 + (lane & 31)) * RS];
    int khalf = (lane >> 5) * 8;

    floatx16 acc0, acc1, acc2, acc3;
    for (int ii = 0; ii < 16; ii++) acc0[ii] = acc1[ii] = acc2[ii] = acc3[ii] = 0.f;

    const ushort* wl8 = wpk + (size_t)lane * 8;
#pragma unroll
    for (int s2 = 0; s2 < 16; s2++) {
        int m = s2 >> 3, s = s2 & 7;
        short8 a = *(const short8*)(arow + m * 128 + s * 16 + khalf);
        size_t fb = (size_t)((m * 8 + s) * 4) * 512;
        short8 b0 = *(const short8*)(wl8 + fb);
        short8 b1 = *(const short8*)(wl8 + fb + 512);
        short8 b2 = *(const short8*)(wl8 + fb + 1024);
        short8 b3 = *(const short8*)(wl8 + fb + 1536);
        acc0 = __builtin_amdgcn_mfma_f32_32x32x16_bf16(a, b0, acc0, 0, 0, 0);
        acc1 = __builtin_amdgcn_mfma_f32_32x32x16_bf16(a, b1, acc1, 0, 0, 0);
        acc2 = __builtin_amdgcn_mfma_f32_32x32x16_bf16(a, b2, acc2, 0, 0, 0);
        acc3 = __builtin_amdgcn_mfma_f32_32x32x16_bf16(a, b3, acc3, 0, 0, 0);
    }

    int col = lane & 31;
    int rbase = 4 * (lane >> 5);
    floatx16 accs[4] = {acc0, acc1, acc2, acc3};
    for (int t4 = 0; t4 < 4; t4++) {
        int n = t4 * 32 + col;
        float bv = bias[n];
#pragma unroll
        for (int r = 0; r < 16; r++) {
            int row = (r & 3) + 8 * (r >> 2) + rbase;
            int gm = m0 + row;
            int gn = node0 + gm;
            if (gn >= N_NODES) continue;
            float v = accs[t4][r] + bv;
            v = (v >= 0.f) ? v : NEG_SLOPE * v;
            if (residual) v += bfraw2f(sA[(size_t)gm * RS + 128 + n]);
            xout[(size_t)gn * DIM + n] = f2bf(v);
        }
    }
}

// ---------------- global mean pool, parallel segment-sum ----------------
__global__ __launch_bounds__(128) void pool_partial(const ushort* __restrict__ xb,
                                                    const int* __restrict__ batch,
                                                    float* __restrict__ pooled) {
    int nb = blockIdx.x * 128;
    int ne = min(nb + 128, N_NODES);
    int d = threadIdx.x;
    int gcur = batch[nb];
    float acc = 0.f;
    for (int n = nb; n < ne; n++) {
        int g = batch[n];
        if (g != gcur) {
            atomicAdd(&pooled[gcur * DIM + d], acc);
            acc = 0.f;
            gcur = g;
        }
        acc += bfraw2f(xb[(size_t)n * DIM + d]);
    }
    atomicAdd(&pooled[gcur * DIM + d], acc);
}

__global__ void pool_final(const float* __restrict__ pooled,
                           const int* __restrict__ gstart,
                           float* __restrict__ out) {
    int i = blockIdx.x * blockDim.x + threadIdx.x;
    if (i >= N_GRAPHS * DIM) return;
    int g = i >> 7;
    int cnt = gstart[g + 1] - gstart[g];
    out[i] = pooled[i] / (float)max(cnt, 1);
}

// ---------------- launch ----------------

extern "C" void kernel_launch(void* const* d_in, const int* in_sizes, int n_in,
                              void* d_out, int out_size, void* d_ws, size_t ws_size,
                              hipStream_t stream) {
    const float* x     = (const float*)d_in[0];
    const int*   ei    = (const int*)d_in[1];
    const int*   batch = (const int*)d_in[2];
    const float* Wl    = (const float*)d_in[3];
    const float* bl    = (const float*)d_in[4];
    const float* Wr    = (const float*)d_in[5];
    float* out = (float*)d_out;

    const int* esrc = ei;
    const int* edst = ei + N_EDGES;

    // workspace layout (ping-pong x buffers: gather reads arbitrary rows while
    // other blocks write -> in-place is a race, so alternate xbA/xbB)
    ushort* xb0 = (ushort*)d_ws;                          // [N,128] bf16
    ushort* xbA = xb0 + (size_t)N_NODES * DIM;            // [N,128] bf16
    ushort* xbB = xbA + (size_t)N_NODES * DIM;            // [N,128] bf16
    ushort* wpk = xbB + (size_t)N_NODES * DIM;            // [4][2][128*128] bf16
    int* deg    = (int*)(wpk + (size_t)N_LAYERS * 2 * DIM * DIM);
    int* fill   = deg + N_NODES;
    int* csr    = fill + N_NODES;
    int* rp     = csr + N_EDGES;
    int* gstart = rp + (N_NODES + 1);
    int* bsum   = gstart + (N_GRAPHS + 1);
    float* pooled = (float*)(bsum + NB_SCAN);             // [G,128] fp32

    zero_ints<<<(2 * N_NODES + 255) / 256, 256, 0, stream>>>(deg, 2 * N_NODES);
    zero_ints<<<(N_GRAPHS * DIM + 255) / 256, 256, 0, stream>>>((int*)pooled, N_GRAPHS * DIM);

    convert_x<<<(N_NODES * DIM / 8 + 255) / 256, 256, 0, stream>>>((const float4*)x, (uint4*)xb0);
    pack_w<<<dim3(32, 2, 4), 64, 0, stream>>>(Wl, Wr, wpk);
    count_deg<<<(N_EDGES + 255) / 256, 256, 0, stream>>>(edst, deg);

    scan_pass1<<<NB_SCAN, 256, 0, stream>>>(deg, bsum);
    scan_pass2<<<1, 256, 0, stream>>>(bsum);
    scan_pass3<<<NB_SCAN, 256, 0, stream>>>(deg, bsum, rp);

    fill_csr<<<(N_EDGES + 255) / 256, 256, 0, stream>>>(esrc, edst, rp, fill, csr);
    graph_start<<<(N_NODES + 255) / 256, 256, 0, stream>>>(batch, gstart);

    int gemm_blocks = (N_NODES + 127) / 128;
    const ushort* xin = xb0;
    ushort* xo = xbA;
    for (int l = 0; l < N_LAYERS; l++) {
        sage_layer<<<gemm_blocks, 256, 0, stream>>>(
            (const uint*)xin, xo, rp, csr, wpk + (size_t)l * 2 * DIM * DIM,
            bl + (size_t)l * DIM, (l >= 2) ? 1 : 0);
        xin = xo;
        xo = (xin == xbA) ? xbB : xbA;
    }

    pool_partial<<<(N_NODES + 127) / 128, 128, 0, stream>>>(xin, batch, pooled);
    pool_final<<<(N_GRAPHS * DIM + 255) / 256, 256, 0, stream>>>(pooled, gstart, out);
}